// Round 3
// baseline (5640.008 us; speedup 1.0000x reference)
//
#include <hip/hip_runtime.h>
#include <hip/hip_bf16.h>
#include <hip/hip_cooperative_groups.h>
#include <cstdio>

namespace cg = cooperative_groups;

typedef __bf16 bf16;
typedef __bf16 bf16x8 __attribute__((ext_vector_type(8)));
typedef __bf16 bf16x4 __attribute__((ext_vector_type(4)));
typedef float f32x4 __attribute__((ext_vector_type(4)));

__device__ __forceinline__ float sigmoidf_(float x) { return 1.f / (1.f + __expf(-x)); }
__device__ __forceinline__ float tanhf_(float x)    { return 1.f - 2.f / (__expf(2.f * x) + 1.f); }

// async global->LDS, 16 bytes per lane. LDS dest must be wave-uniform base +
// lane*16 (m104/m108) — all call sites index LDS with (tid-contiguous)*16B.
__device__ __forceinline__ void gld_lds16(const bf16* g, bf16* l) {
    __builtin_amdgcn_global_load_lds(
        (const __attribute__((address_space(1))) void*)g,
        (__attribute__((address_space(3))) void*)l, 16, 0, 0);
}

// ---------------------------------------------------------------------------
// m97-structure bf16 GEMM: C[M,N] = A[M,K] * B[N,K]^T + bias[N]
// ---------------------------------------------------------------------------
template<int BM, int BN, bool OUTBF16, bool NBOUND>
__global__ __launch_bounds__(256)
void gemm_lds_k(const bf16* __restrict__ A, const bf16* __restrict__ B,
                void* __restrict__ Cv, const float* __restrict__ bias,
                int K, int lda, int ldb, int ldc, int Nlim)
{
    constexpr int TM = BM / 32;
    constexpr int TN = BN / 32;

    __shared__ __align__(16) bf16 As[BM * 32];
    __shared__ __align__(16) bf16 Bs[BN * 32];

    const int tid  = threadIdx.x;
    const int wave = tid >> 6;
    const int lane = tid & 63;
    const int lrow = lane & 15;
    const int q    = lane >> 4;

    const int rowbase = blockIdx.y * BM;
    const int colbase = blockIdx.x * BN;
    const int wr = (wave >> 1) * (BM / 2);
    const int wc = (wave & 1) * (BN / 2);

    f32x4 acc[TM][TN] = {};

    for (int kk = 0; kk < K; kk += 32) {
        __syncthreads();
        #pragma unroll
        for (int i = 0; i < BM / 64; ++i) {
            int c  = tid + i * 256;
            int r  = c >> 2;
            int kc = (c & 3) * 8;
            gld_lds16(A + (size_t)(rowbase + r) * lda + kk + kc, &As[c * 8]);
        }
        #pragma unroll
        for (int i = 0; i < BN / 64; ++i) {
            int c  = tid + i * 256;
            int r  = c >> 2;
            int kc = (c & 3) * 8;
            gld_lds16(B + (size_t)(colbase + r) * ldb + kk + kc, &Bs[c * 8]);
        }
        __syncthreads();

        bf16x8 afr[TM], bfr[TN];
        #pragma unroll
        for (int m = 0; m < TM; ++m)
            afr[m] = *(const bf16x8*)&As[(wr + m * 16 + lrow) * 32 + q * 8];
        #pragma unroll
        for (int n = 0; n < TN; ++n)
            bfr[n] = *(const bf16x8*)&Bs[(wc + n * 16 + lrow) * 32 + q * 8];
        #pragma unroll
        for (int m = 0; m < TM; ++m)
            #pragma unroll
            for (int n = 0; n < TN; ++n)
                acc[m][n] = __builtin_amdgcn_mfma_f32_16x16x32_bf16(
                                afr[m], bfr[n], acc[m][n], 0, 0, 0);
    }

    #pragma unroll
    for (int m = 0; m < TM; ++m) {
        #pragma unroll
        for (int n = 0; n < TN; ++n) {
            int gr0 = rowbase + wr + m * 16 + q * 4;
            int gc  = colbase + wc + n * 16 + lrow;
            bool cok = (!NBOUND) || (gc < Nlim);
            float bv = cok ? bias[gc] : 0.f;
            #pragma unroll
            for (int rix = 0; rix < 4; ++rix) {
                if (cok) {
                    float v = acc[m][n][rix] + bv;
                    size_t o = (size_t)(gr0 + rix) * ldc + gc;
                    if (OUTBF16) ((bf16*)Cv)[o] = (bf16)v;
                    else         ((float*)Cv)[o] = v;
                }
            }
        }
    }
}

// ---------------------------------------------------------------------------
// Fallback big GEMM (fp32 operands, cast during staging) if ws too small.
// ---------------------------------------------------------------------------
template<int BM, int BN>
__global__ __launch_bounds__(256)
void gemm_cast_k(const float* __restrict__ Av, const float* __restrict__ Bv,
                 bf16* __restrict__ Cv, const float* __restrict__ bias,
                 int K, int Klim, int lda, int ldb, int ldc)
{
    constexpr int TM = BM / 32;
    constexpr int TN = BN / 32;
    constexpr int LDK = 40;

    __shared__ __align__(16) bf16 As[BM * LDK];
    __shared__ __align__(16) bf16 Bs[BN * LDK];

    const int tid  = threadIdx.x;
    const int wave = tid >> 6;
    const int lane = tid & 63;
    const int lrow = lane & 15;
    const int q    = lane >> 4;

    const int rowbase = blockIdx.y * BM;
    const int colbase = blockIdx.x * BN;
    const int wr = (wave >> 1) * (BM / 2);
    const int wc = (wave & 1) * (BN / 2);

    f32x4 acc[TM][TN] = {};

    for (int kk = 0; kk < K; kk += 32) {
        __syncthreads();
        #pragma unroll
        for (int i = 0; i < BM / 64; ++i) {
            int c = tid + i * 256;
            int r = c >> 2, kc = (c & 3) * 8, kg = kk + kc;
            const float* src = Av + (size_t)(rowbase + r) * lda + kg;
            bf16x8 v;
            if (kg + 8 <= Klim) {
                float4 f0 = *(const float4*)(src);
                float4 f1 = *(const float4*)(src + 4);
                v[0]=(bf16)f0.x; v[1]=(bf16)f0.y; v[2]=(bf16)f0.z; v[3]=(bf16)f0.w;
                v[4]=(bf16)f1.x; v[5]=(bf16)f1.y; v[6]=(bf16)f1.z; v[7]=(bf16)f1.w;
            } else {
                #pragma unroll
                for (int e = 0; e < 8; ++e) v[e] = (kg + e < Klim) ? (bf16)src[e] : (bf16)0.f;
            }
            *(bf16x8*)&As[r * LDK + kc] = v;
        }
        #pragma unroll
        for (int i = 0; i < BN / 64; ++i) {
            int c = tid + i * 256;
            int r = c >> 2, kc = (c & 3) * 8, kg = kk + kc;
            const float* src = Bv + (size_t)(colbase + r) * ldb + kg;
            bf16x8 v;
            if (kg + 8 <= Klim) {
                float4 f0 = *(const float4*)(src);
                float4 f1 = *(const float4*)(src + 4);
                v[0]=(bf16)f0.x; v[1]=(bf16)f0.y; v[2]=(bf16)f0.z; v[3]=(bf16)f0.w;
                v[4]=(bf16)f1.x; v[5]=(bf16)f1.y; v[6]=(bf16)f1.z; v[7]=(bf16)f1.w;
            } else {
                #pragma unroll
                for (int e = 0; e < 8; ++e) v[e] = (kg + e < Klim) ? (bf16)src[e] : (bf16)0.f;
            }
            *(bf16x8*)&Bs[r * LDK + kc] = v;
        }
        __syncthreads();

        bf16x8 afr[TM], bfr[TN];
        #pragma unroll
        for (int m = 0; m < TM; ++m)
            afr[m] = *(const bf16x8*)&As[(wr + m * 16 + lrow) * LDK + q * 8];
        #pragma unroll
        for (int n = 0; n < TN; ++n)
            bfr[n] = *(const bf16x8*)&Bs[(wc + n * 16 + lrow) * LDK + q * 8];
        #pragma unroll
        for (int m = 0; m < TM; ++m)
            #pragma unroll
            for (int n = 0; n < TN; ++n)
                acc[m][n] = __builtin_amdgcn_mfma_f32_16x16x32_bf16(
                                afr[m], bfr[n], acc[m][n], 0, 0, 0);
    }

    #pragma unroll
    for (int m = 0; m < TM; ++m) {
        #pragma unroll
        for (int n = 0; n < TN; ++n) {
            int gr0 = rowbase + wr + m * 16 + q * 4;
            int gc  = colbase + wc + n * 16 + lrow;
            float bv = bias[gc];
            #pragma unroll
            for (int rix = 0; rix < 4; ++rix)
                Cv[(size_t)(gr0 + rix) * ldc + gc] = (bf16)(acc[m][n][rix] + bv);
        }
    }
}

// ---------------------------------------------------------------------------
// Persistent recurrence kernel (cooperative launch, grid = 512 = 2 blocks/CU).
// Block owns 128 batches x 4 h-cols x 5 gates. Its W_state slice (20 rows x
// 1024 k, cast to bf16) lives in LDS [32 kc][32 col][32 k] (cols 20..31 zero)
// for ALL 32 timesteps. c-state + dropout mask live in registers. h_prev is
// read from global each step (512 KB, L2-resident). grid.sync() between steps.
// Wave w: batches [32w, 32w+32): A-frags m=0/1; B col-groups cg=0/1
// (cols 0..15, 16..31). col = g*4 + hi for g<5, hi<4.
// ---------------------------------------------------------------------------
__global__ __launch_bounds__(256, 2)
void step_persist_k(const float* __restrict__ Wst,      // [5120][1024] fp32
                    const bf16*  __restrict__ pi,       // [32][256][6144]
                    const float* __restrict__ b_state,  // [5120]
                    const float* __restrict__ c0,       // [256][1024]
                    const float* __restrict__ dmask,    // [256][1024]
                    bf16* __restrict__ hs)              // [33][256][1024]
{
    __shared__ __align__(16) bf16 Bws[32 * 32 * 32];    // 64 KB

    cg::grid_group grid = cg::this_grid();

    const int tid   = threadIdx.x;
    const int hbase = (blockIdx.x >> 1) * 4;
    const int bbase = (blockIdx.x & 1) * 128;
    const int wv    = tid >> 6;
    const int lane  = tid & 63;
    const int lrow  = lane & 15;
    const int q     = lane >> 4;
    const int hi4   = lrow & 3;
    const int msel  = (lrow >> 2) & 1;

    // ---- load W slice into LDS once (fp32 -> bf16), zero pad cols ----
    for (int p4 = tid; p4 < 8192; p4 += 256) {
        int e   = p4 * 4;
        int kc  = e >> 10;
        int col = (e >> 5) & 31;
        int k   = e & 31;
        bf16x4 v;
        if (col < 20) {
            int row = (col >> 2) * 1024 + hbase + (col & 3);
            float4 f = *(const float4*)(Wst + (size_t)row * 1024 + kc * 32 + k);
            v[0]=(bf16)f.x; v[1]=(bf16)f.y; v[2]=(bf16)f.z; v[3]=(bf16)f.w;
        } else {
            v[0]=v[1]=v[2]=v[3]=(bf16)0.f;
        }
        *(bf16x4*)&Bws[e] = v;
    }
    __syncthreads();

    // ---- per-lane persistent state ----
    const int hcol = hbase + hi4;                       // global h index
    const int brow = bbase + (wv << 5) + (msel << 4) + (q << 2);  // + rix
    float bs[5], cr[4], dm[4];
    #pragma unroll
    for (int g = 0; g < 5; ++g) bs[g] = b_state[g * 1024 + hcol];
    #pragma unroll
    for (int rix = 0; rix < 4; ++rix) {
        size_t j = (size_t)(brow + rix) * 1024 + hcol;
        cr[rix] = c0[j];
        dm[rix] = dmask[j];
    }

    const int ar0 = bbase + (wv << 5) + lrow;           // A-frag m=0 row
    const int ar1 = ar0 + 16;                           // m=1

    for (int t = 0; t < 32; ++t) {
        const bf16* hp  = hs + (size_t)t * 262144;
        const bf16* pa0 = hp + (size_t)ar0 * 1024 + q * 8;
        const bf16* pa1 = hp + (size_t)ar1 * 1024 + q * 8;

        f32x4 a00 = {}, a01 = {}, a10 = {}, a11 = {};
        #pragma unroll 4
        for (int kc = 0; kc < 32; ++kc) {
            bf16x8 x0 = *(const bf16x8*)(pa0 + kc * 32);
            bf16x8 x1 = *(const bf16x8*)(pa1 + kc * 32);
            bf16x8 w0 = *(const bf16x8*)&Bws[(kc * 32 + lrow) * 32 + q * 8];
            bf16x8 w1 = *(const bf16x8*)&Bws[(kc * 32 + 16 + lrow) * 32 + q * 8];
            a00 = __builtin_amdgcn_mfma_f32_16x16x32_bf16(x0, w0, a00, 0, 0, 0);
            a01 = __builtin_amdgcn_mfma_f32_16x16x32_bf16(x0, w1, a01, 0, 0, 0);
            a10 = __builtin_amdgcn_mfma_f32_16x16x32_bf16(x1, w0, a10, 0, 0, 0);
            a11 = __builtin_amdgcn_mfma_f32_16x16x32_bf16(x1, w1, a11, 0, 0, 0);
        }

        bf16* hn = hs + (size_t)(t + 1) * 262144;
        const bf16* pit = pi + (size_t)t * 1572864;

        #pragma unroll
        for (int rix = 0; rix < 4; ++rix) {
            // gather the 5 gate projections for (batch brow+rix, h hcol).
            // source lane (same q-group): col g*4+hi (cg0, g<4) or hi (cg1).
            float p[5];
            #pragma unroll
            for (int g = 0; g < 5; ++g) {
                int src = (q << 4) + ((g < 4) ? (g * 4 + hi4) : hi4);
                float v0, v1;
                if (g < 4) { v0 = __shfl(a00[rix], src, 64); v1 = __shfl(a10[rix], src, 64); }
                else       { v0 = __shfl(a01[rix], src, 64); v1 = __shfl(a11[rix], src, 64); }
                p[g] = msel ? v1 : v0;
            }
            if (lrow < 8) {
                int b = brow + rix;
                const bf16* pib = pit + (size_t)b * 6144 + hcol;
                float p0 = p[0] + bs[0] + (float)pib[0];
                float p1 = p[1] + bs[1] + (float)pib[1024];
                float p2 = p[2] + bs[2] + (float)pib[2048];
                float p3 = p[3] + bs[3] + (float)pib[3072];
                float p4 = p[4] + bs[4] + (float)pib[4096];
                float p5 = (float)pib[5120];

                float ig = sigmoidf_(p0);
                float fg = sigmoidf_(p1);
                float mi = tanhf_(p2);
                float og = sigmoidf_(p3);
                float hw = sigmoidf_(p4);

                float mem = ig * mi + fg * cr[rix];
                cr[rix] = mem;
                float out = og * tanhf_(mem);
                out = hw * out + (1.f - hw) * p5;
                out *= dm[rix];
                hn[(size_t)b * 1024 + hcol] = (bf16)out;
            }
        }
        __threadfence();    // agent-scope release: flush h writes past XCD L2
        grid.sync();
        __threadfence();    // agent-scope acquire: invalidate stale h lines
    }
}

// ---------------------------------------------------------------------------
// casts
// ---------------------------------------------------------------------------
__global__ void cast_f2b4_k(const float* __restrict__ src, bf16* __restrict__ dst, int n4) {
    int i = blockIdx.x * 256 + threadIdx.x;
    if (i < n4) {
        float4 f = *(const float4*)(src + i * 4);
        bf16x4 v; v[0]=(bf16)f.x; v[1]=(bf16)f.y; v[2]=(bf16)f.z; v[3]=(bf16)f.w;
        *(bf16x4*)(dst + i * 4) = v;
    }
}

// W_out [C,H] -> bf16 [192,H], rows >= C zero-filled
__global__ void cast_wout_k(const float* __restrict__ src, bf16* __restrict__ dst, int Crows) {
    int i = blockIdx.x * 256 + threadIdx.x;    // over 192*1024
    int r = i >> 10;
    dst[i] = (r < Crows) ? (bf16)src[i] : (bf16)0.f;
}

// row-wise cast with K padding (vec4): src [rows, klim] f32 -> dst [rows, kp] bf16
__global__ void cast_pad4_k(const float* __restrict__ src, bf16* __restrict__ dst,
                            int klim, int kp) {
    int r = blockIdx.x;
    const float* s = src + (size_t)r * klim;
    bf16* d = dst + (size_t)r * kp;
    int nk4 = kp >> 2, lim4 = klim >> 2;
    for (int c = threadIdx.x; c < nk4; c += 256) {
        bf16x4 v;
        if (c < lim4) {
            float4 f = *(const float4*)(s + c * 4);
            v[0]=(bf16)f.x; v[1]=(bf16)f.y; v[2]=(bf16)f.z; v[3]=(bf16)f.w;
        } else {
            v[0]=v[1]=v[2]=v[3]=(bf16)0.f;
        }
        *(bf16x4*)(d + c * 4) = v;
    }
}

// ---------------------------------------------------------------------------
extern "C" void kernel_launch(void* const* d_in, const int* in_sizes, int n_in,
                              void* d_out, int out_size, void* d_ws, size_t ws_size,
                              hipStream_t stream)
{
    const float* x       = (const float*)d_in[0];
    const float* h0      = (const float*)d_in[1];
    const float* c0      = (const float*)d_in[2];
    const float* dmask   = (const float*)d_in[3];
    const float* W_in    = (const float*)d_in[4];
    const float* b_in    = (const float*)d_in[5];
    const float* W_state = (const float*)d_in[6];
    const float* b_state = (const float*)d_in[7];
    const float* W_out   = (const float*)d_in[8];
    const float* b_out   = (const float*)d_in[9];

    constexpr int T = 32, B = 256, DIN = 4196, H = 1024, C = 151;
    constexpr int M  = T * B;       // 8192
    constexpr int KP = 4224;        // DIN padded to multiple of 32
    constexpr int N6 = 6 * H;       // 6144

    size_t off = 0;
    auto carve = [&](size_t bytes) -> void* {
        void* p = (char*)d_ws + off;
        off += (bytes + 255) & ~(size_t)255;
        return p;
    };
    bf16* pi  = (bf16*)carve((size_t)M * N6 * 2);           // 100.7 MB
    bf16* wob = (bf16*)carve((size_t)192 * H * 2);          //   0.4 MB
    bf16* hs  = (bf16*)carve((size_t)(T + 1) * B * H * 2);  //  17.3 MB
    size_t base_need = off;

    bf16 *xb = nullptr, *wb = nullptr;
    bool precast = (ws_size >= base_need + (size_t)M * KP * 2 + (size_t)N6 * KP * 2 + 1024);
    if (precast) {
        xb = (bf16*)carve((size_t)M * KP * 2);              // 69.2 MB
        wb = (bf16*)carve((size_t)N6 * KP * 2);             // 51.9 MB
    }
    if (ws_size < base_need) {
        fprintf(stderr, "kernel_launch: ws too small (%zu < %zu)\n", ws_size, base_need);
        return;
    }

    // ---- weight cast + h0 -> hs slot 0 ----
    hipLaunchKernelGGL(cast_wout_k, dim3(192 * H / 256), dim3(256), 0, stream, W_out, wob, C);
    hipLaunchKernelGGL(cast_f2b4_k, dim3(B * H / 4 / 256), dim3(256), 0, stream,
                       h0, hs, B * H / 4);

    // ---- big input-projection GEMM: pi = bf16(X @ W_in^T + b_in) ----
    if (precast) {
        hipLaunchKernelGGL(cast_pad4_k, dim3(M),  dim3(256), 0, stream, x,    xb, DIN, KP);
        hipLaunchKernelGGL(cast_pad4_k, dim3(N6), dim3(256), 0, stream, W_in, wb, DIN, KP);
        hipLaunchKernelGGL((gemm_lds_k<128, 128, true, false>),
                           dim3(N6 / 128, M / 128), dim3(256), 0, stream,
                           xb, wb, pi, b_in, KP, KP, KP, N6, N6);
    } else {
        hipLaunchKernelGGL((gemm_cast_k<128, 128>),
                           dim3(N6 / 128, M / 128), dim3(256), 0, stream,
                           x, W_in, pi, b_in, KP, DIN, DIN, DIN, N6);
    }

    // ---- persistent cooperative recurrence: one kernel, 32 grid syncs ----
    {
        const float* Wst_ = W_state;
        const float* bst_ = b_state;
        const float* c0_  = c0;
        const float* dm_  = dmask;
        bf16* pi_ = pi;
        bf16* hs_ = hs;
        void* args[] = { (void*)&Wst_, (void*)&pi_, (void*)&bst_,
                         (void*)&c0_, (void*)&dm_, (void*)&hs_ };
        hipLaunchCooperativeKernel(reinterpret_cast<void*>(step_persist_k),
                                   dim3(512), dim3(256), args, 0, stream);
    }

    // ---- output projection: logits = hs @ W_out^T + b_out ----
    hipLaunchKernelGGL((gemm_lds_k<128, 64, false, true>),
                       dim3(192 / 64, M / 128), dim3(256), 0, stream,
                       hs + (size_t)B * H, wob, (float*)d_out, b_out,
                       H, H, H, C, C);
}

// Round 4
// 1300.667 us; speedup vs baseline: 4.3362x; 4.3362x over previous
//
#include <hip/hip_runtime.h>
#include <hip/hip_bf16.h>
#include <cstdio>

typedef __bf16 bf16;
typedef __bf16 bf16x8 __attribute__((ext_vector_type(8)));
typedef __bf16 bf16x4 __attribute__((ext_vector_type(4)));
typedef float f32x4 __attribute__((ext_vector_type(4)));

__device__ __forceinline__ float sigmoidf_(float x) { return 1.f / (1.f + __expf(-x)); }
__device__ __forceinline__ float tanhf_(float x)    { return 1.f - 2.f / (__expf(2.f * x) + 1.f); }

// async global->LDS, 16 bytes per lane. LDS dest must be wave-uniform base +
// lane*16 (m104/m108) — all call sites index LDS with (chunk-contiguous)*16B
// where chunk is tid-consecutive within the wave.
__device__ __forceinline__ void gld_lds16(const bf16* g, bf16* l) {
    __builtin_amdgcn_global_load_lds(
        (const __attribute__((address_space(1))) void*)g,
        (__attribute__((address_space(3))) void*)l, 16, 0, 0);
}

// ---------------------------------------------------------------------------
// m97-structure bf16 GEMM: C[M,N] = A[M,K] * B[N,K]^T + bias[N]
// ---------------------------------------------------------------------------
template<int BM, int BN, bool OUTBF16, bool NBOUND>
__global__ __launch_bounds__(256)
void gemm_lds_k(const bf16* __restrict__ A, const bf16* __restrict__ B,
                void* __restrict__ Cv, const float* __restrict__ bias,
                int K, int lda, int ldb, int ldc, int Nlim)
{
    constexpr int TM = BM / 32;
    constexpr int TN = BN / 32;

    __shared__ __align__(16) bf16 As[BM * 32];
    __shared__ __align__(16) bf16 Bs[BN * 32];

    const int tid  = threadIdx.x;
    const int wave = tid >> 6;
    const int lane = tid & 63;
    const int lrow = lane & 15;
    const int q    = lane >> 4;

    const int rowbase = blockIdx.y * BM;
    const int colbase = blockIdx.x * BN;
    const int wr = (wave >> 1) * (BM / 2);
    const int wc = (wave & 1) * (BN / 2);

    f32x4 acc[TM][TN] = {};

    for (int kk = 0; kk < K; kk += 32) {
        __syncthreads();
        #pragma unroll
        for (int i = 0; i < BM / 64; ++i) {
            int c  = tid + i * 256;
            int r  = c >> 2;
            int kc = (c & 3) * 8;
            gld_lds16(A + (size_t)(rowbase + r) * lda + kk + kc, &As[c * 8]);
        }
        #pragma unroll
        for (int i = 0; i < BN / 64; ++i) {
            int c  = tid + i * 256;
            int r  = c >> 2;
            int kc = (c & 3) * 8;
            gld_lds16(B + (size_t)(colbase + r) * ldb + kk + kc, &Bs[c * 8]);
        }
        __syncthreads();

        bf16x8 afr[TM], bfr[TN];
        #pragma unroll
        for (int m = 0; m < TM; ++m)
            afr[m] = *(const bf16x8*)&As[(wr + m * 16 + lrow) * 32 + q * 8];
        #pragma unroll
        for (int n = 0; n < TN; ++n)
            bfr[n] = *(const bf16x8*)&Bs[(wc + n * 16 + lrow) * 32 + q * 8];
        #pragma unroll
        for (int m = 0; m < TM; ++m)
            #pragma unroll
            for (int n = 0; n < TN; ++n)
                acc[m][n] = __builtin_amdgcn_mfma_f32_16x16x32_bf16(
                                afr[m], bfr[n], acc[m][n], 0, 0, 0);
    }

    #pragma unroll
    for (int m = 0; m < TM; ++m) {
        #pragma unroll
        for (int n = 0; n < TN; ++n) {
            int gr0 = rowbase + wr + m * 16 + q * 4;
            int gc  = colbase + wc + n * 16 + lrow;
            bool cok = (!NBOUND) || (gc < Nlim);
            float bv = cok ? bias[gc] : 0.f;
            #pragma unroll
            for (int rix = 0; rix < 4; ++rix) {
                if (cok) {
                    float v = acc[m][n][rix] + bv;
                    size_t o = (size_t)(gr0 + rix) * ldc + gc;
                    if (OUTBF16) ((bf16*)Cv)[o] = (bf16)v;
                    else         ((float*)Cv)[o] = v;
                }
            }
        }
    }
}

// ---------------------------------------------------------------------------
// Fallback big GEMM (fp32 operands, cast during staging) if ws too small.
// ---------------------------------------------------------------------------
template<int BM, int BN>
__global__ __launch_bounds__(256)
void gemm_cast_k(const float* __restrict__ Av, const float* __restrict__ Bv,
                 bf16* __restrict__ Cv, const float* __restrict__ bias,
                 int K, int Klim, int lda, int ldb, int ldc)
{
    constexpr int TM = BM / 32;
    constexpr int TN = BN / 32;
    constexpr int LDK = 40;

    __shared__ __align__(16) bf16 As[BM * LDK];
    __shared__ __align__(16) bf16 Bs[BN * LDK];

    const int tid  = threadIdx.x;
    const int wave = tid >> 6;
    const int lane = tid & 63;
    const int lrow = lane & 15;
    const int q    = lane >> 4;

    const int rowbase = blockIdx.y * BM;
    const int colbase = blockIdx.x * BN;
    const int wr = (wave >> 1) * (BM / 2);
    const int wc = (wave & 1) * (BN / 2);

    f32x4 acc[TM][TN] = {};

    for (int kk = 0; kk < K; kk += 32) {
        __syncthreads();
        #pragma unroll
        for (int i = 0; i < BM / 64; ++i) {
            int c = tid + i * 256;
            int r = c >> 2, kc = (c & 3) * 8, kg = kk + kc;
            const float* src = Av + (size_t)(rowbase + r) * lda + kg;
            bf16x8 v;
            if (kg + 8 <= Klim) {
                float4 f0 = *(const float4*)(src);
                float4 f1 = *(const float4*)(src + 4);
                v[0]=(bf16)f0.x; v[1]=(bf16)f0.y; v[2]=(bf16)f0.z; v[3]=(bf16)f0.w;
                v[4]=(bf16)f1.x; v[5]=(bf16)f1.y; v[6]=(bf16)f1.z; v[7]=(bf16)f1.w;
            } else {
                #pragma unroll
                for (int e = 0; e < 8; ++e) v[e] = (kg + e < Klim) ? (bf16)src[e] : (bf16)0.f;
            }
            *(bf16x8*)&As[r * LDK + kc] = v;
        }
        #pragma unroll
        for (int i = 0; i < BN / 64; ++i) {
            int c = tid + i * 256;
            int r = c >> 2, kc = (c & 3) * 8, kg = kk + kc;
            const float* src = Bv + (size_t)(colbase + r) * ldb + kg;
            bf16x8 v;
            if (kg + 8 <= Klim) {
                float4 f0 = *(const float4*)(src);
                float4 f1 = *(const float4*)(src + 4);
                v[0]=(bf16)f0.x; v[1]=(bf16)f0.y; v[2]=(bf16)f0.z; v[3]=(bf16)f0.w;
                v[4]=(bf16)f1.x; v[5]=(bf16)f1.y; v[6]=(bf16)f1.z; v[7]=(bf16)f1.w;
            } else {
                #pragma unroll
                for (int e = 0; e < 8; ++e) v[e] = (kg + e < Klim) ? (bf16)src[e] : (bf16)0.f;
            }
            *(bf16x8*)&Bs[r * LDK + kc] = v;
        }
        __syncthreads();

        bf16x8 afr[TM], bfr[TN];
        #pragma unroll
        for (int m = 0; m < TM; ++m)
            afr[m] = *(const bf16x8*)&As[(wr + m * 16 + lrow) * LDK + q * 8];
        #pragma unroll
        for (int n = 0; n < TN; ++n)
            bfr[n] = *(const bf16x8*)&Bs[(wc + n * 16 + lrow) * LDK + q * 8];
        #pragma unroll
        for (int m = 0; m < TM; ++m)
            #pragma unroll
            for (int n = 0; n < TN; ++n)
                acc[m][n] = __builtin_amdgcn_mfma_f32_16x16x32_bf16(
                                afr[m], bfr[n], acc[m][n], 0, 0, 0);
    }

    #pragma unroll
    for (int m = 0; m < TM; ++m) {
        #pragma unroll
        for (int n = 0; n < TN; ++n) {
            int gr0 = rowbase + wr + m * 16 + q * 4;
            int gc  = colbase + wc + n * 16 + lrow;
            float bv = bias[gc];
            #pragma unroll
            for (int rix = 0; rix < 4; ++rix)
                Cv[(size_t)(gr0 + rix) * ldc + gc] = (bf16)(acc[m][n][rix] + bv);
        }
    }
}

// ---------------------------------------------------------------------------
// Fused recurrent step v2. Block = 512 threads (8 waves), grid (H/16=64, B/64=4).
// Block tile: 64 batch x (5 gates x 16 h) x K=1024. K is split in two halves,
// one per 4-wave group; each group runs its own 8-iteration async-staged
// pipeline in private LDS buffers, then halves are summed via LDS and gates
// applied in-register (no shuffles: wave wg owns m-tile wg; lane (q,lrow,rix)
// owns batch bbase+wg*16+q*4+rix, h hbase+lrow, for all 5 gates).
// Epilogue operands (pi, cst, dmask, b_state) prefetched at kernel entry.
// ---------------------------------------------------------------------------
__global__ __launch_bounds__(512)
void step_k2(const bf16*  __restrict__ hprev,   // [256][1024]
             const bf16*  __restrict__ wsb,     // [5120][1024]
             const bf16*  __restrict__ pi_t,    // [256][6144] (b_in included)
             const float* __restrict__ b_state, // [5120]
             float*       __restrict__ cst,     // [256][1024]
             const float* __restrict__ dmask,   // [256][1024]
             bf16*        __restrict__ hnext)   // [256][1024]
{
    // 36 KB: A[2][4096] (16KB) + B[2][5120] (20KB); epilogue reduction (20KB
    // of floats) aliases the front.
    __shared__ __align__(16) unsigned char smem[36864];
    bf16* Asb = (bf16*)smem;                 // [g2][ks*2048 + r*32 + k]
    bf16* Bsb = (bf16*)(smem + 16384);       // [g2][g*1024 + ks*512 + hh*32 + k]
    float* red = (float*)smem;               // [256][5][4]

    const int tid   = threadIdx.x;
    const int wv    = tid >> 6;
    const int g2    = wv >> 2;               // K-half group
    const int wg    = wv & 3;                // m-tile within group
    const int lane  = tid & 63;
    const int lrow  = lane & 15;
    const int q     = lane >> 4;
    const int lt    = tid & 255;             // thread id within group
    const int hbase = blockIdx.x * 16;
    const int bbase = blockIdx.y * 64;
    const int kbase = g2 * 512;

    bf16* Ag = Asb + g2 * 4096;
    bf16* Bg = Bsb + g2 * 5120;

    // ---- prefetch epilogue operands (group 0 only; drain during iter 0) ----
    const int b0   = bbase + wg * 16 + q * 4;
    const int hcol = hbase + lrow;
    bf16  pif[4][6];
    float crv[4], dmv[4], bsv[5];
    if (g2 == 0) {
        #pragma unroll
        for (int rix = 0; rix < 4; ++rix) {
            const bf16* pib = pi_t + (size_t)(b0 + rix) * 6144 + hcol;
            #pragma unroll
            for (int g = 0; g < 6; ++g) pif[rix][g] = pib[g * 1024];
            size_t j = (size_t)(b0 + rix) * 1024 + hcol;
            crv[rix] = cst[j];
            dmv[rix] = dmask[j];
        }
        #pragma unroll
        for (int g = 0; g < 5; ++g) bsv[g] = b_state[g * 1024 + hcol];
    }

    // ---- K-half pipeline: 8 iters of BK=64 ----
    f32x4 acc[5] = {};
    for (int it = 0; it < 8; ++it) {
        const int kb = kbase + it * 64;
        __syncthreads();
        // A tile: 64 rows x 64 k -> 512 chunks, layout [ks][64][32]
        #pragma unroll
        for (int i = 0; i < 2; ++i) {
            int c  = lt + i * 256;
            int ks = c >> 8, r = (c >> 2) & 63, kk = (c & 3) * 8;
            gld_lds16(hprev + (size_t)(bbase + r) * 1024 + kb + ks * 32 + kk,
                      Ag + c * 8);
        }
        // B tile: 5 gates x 16 rows x 64 k -> 640 chunks, layout [g][ks][16][32]
        #pragma unroll
        for (int i = 0; i < 3; ++i) {
            int c = lt + i * 256;
            if (c < 640) {
                int g = c >> 7, c7 = c & 127;
                int ks = c7 >> 6, hh = (c7 >> 2) & 15, kk = (c & 3) * 8;
                gld_lds16(wsb + (size_t)(g * 1024 + hbase + hh) * 1024
                              + kb + ks * 32 + kk,
                          Bg + c * 8);
            }
        }
        __syncthreads();

        #pragma unroll
        for (int ks = 0; ks < 2; ++ks) {
            bf16x8 af = *(const bf16x8*)&Ag[ks * 2048 + (wg * 16 + lrow) * 32 + q * 8];
            #pragma unroll
            for (int g = 0; g < 5; ++g) {
                bf16x8 bv = *(const bf16x8*)&Bg[g * 1024 + ks * 512 + lrow * 32 + q * 8];
                acc[g] = __builtin_amdgcn_mfma_f32_16x16x32_bf16(af, bv, acc[g], 0, 0, 0);
            }
        }
    }

    // ---- combine K-halves ----
    __syncthreads();
    if (g2 == 1) {
        #pragma unroll
        for (int g = 0; g < 5; ++g)
            *(f32x4*)&red[(lt * 5 + g) * 4] = acc[g];
    }
    __syncthreads();
    if (g2 == 0) {
        #pragma unroll
        for (int g = 0; g < 5; ++g)
            acc[g] += *(const f32x4*)&red[(lt * 5 + g) * 4];

        #pragma unroll
        for (int rix = 0; rix < 4; ++rix) {
            int b = b0 + rix;
            float p0 = acc[0][rix] + bsv[0] + (float)pif[rix][0];
            float p1 = acc[1][rix] + bsv[1] + (float)pif[rix][1];
            float p2 = acc[2][rix] + bsv[2] + (float)pif[rix][2];
            float p3 = acc[3][rix] + bsv[3] + (float)pif[rix][3];
            float p4 = acc[4][rix] + bsv[4] + (float)pif[rix][4];
            float p5 = (float)pif[rix][5];

            float ig = sigmoidf_(p0);
            float fg = sigmoidf_(p1);
            float mi = tanhf_(p2);
            float og = sigmoidf_(p3);
            float hw = sigmoidf_(p4);

            size_t j = (size_t)b * 1024 + hcol;
            float mem = ig * mi + fg * crv[rix];
            cst[j] = mem;
            float out = og * tanhf_(mem);
            out = hw * out + (1.f - hw) * p5;
            out *= dmv[rix];
            hnext[j] = (bf16)out;
        }
    }
}

// ---------------------------------------------------------------------------
// casts / init
// ---------------------------------------------------------------------------
__global__ void cast_f2b4_k(const float* __restrict__ src, bf16* __restrict__ dst, int n4) {
    int i = blockIdx.x * 256 + threadIdx.x;
    if (i < n4) {
        float4 f = *(const float4*)(src + i * 4);
        bf16x4 v; v[0]=(bf16)f.x; v[1]=(bf16)f.y; v[2]=(bf16)f.z; v[3]=(bf16)f.w;
        *(bf16x4*)(dst + i * 4) = v;
    }
}

// W_out [C,H] -> bf16 [192,H], rows >= C zero-filled
__global__ void cast_wout_k(const float* __restrict__ src, bf16* __restrict__ dst, int Crows) {
    int i = blockIdx.x * 256 + threadIdx.x;    // over 192*1024
    int r = i >> 10;
    dst[i] = (r < Crows) ? (bf16)src[i] : (bf16)0.f;
}

// row-wise cast with K padding (vec4): src [rows, klim] f32 -> dst [rows, kp] bf16
__global__ void cast_pad4_k(const float* __restrict__ src, bf16* __restrict__ dst,
                            int klim, int kp) {
    int r = blockIdx.x;
    const float* s = src + (size_t)r * klim;
    bf16* d = dst + (size_t)r * kp;
    int nk4 = kp >> 2, lim4 = klim >> 2;
    for (int c = threadIdx.x; c < nk4; c += 256) {
        bf16x4 v;
        if (c < lim4) {
            float4 f = *(const float4*)(s + c * 4);
            v[0]=(bf16)f.x; v[1]=(bf16)f.y; v[2]=(bf16)f.z; v[3]=(bf16)f.w;
        } else {
            v[0]=v[1]=v[2]=v[3]=(bf16)0.f;
        }
        *(bf16x4*)(d + c * 4) = v;
    }
}

__global__ void init_state_k(const float* __restrict__ c0, const float* __restrict__ h0,
                             float* __restrict__ cst, bf16* __restrict__ hs0) {
    int i = blockIdx.x * 256 + threadIdx.x;
    cst[i] = c0[i];
    hs0[i] = (bf16)h0[i];
}

// ---------------------------------------------------------------------------
extern "C" void kernel_launch(void* const* d_in, const int* in_sizes, int n_in,
                              void* d_out, int out_size, void* d_ws, size_t ws_size,
                              hipStream_t stream)
{
    const float* x       = (const float*)d_in[0];
    const float* h0      = (const float*)d_in[1];
    const float* c0      = (const float*)d_in[2];
    const float* dmask   = (const float*)d_in[3];
    const float* W_in    = (const float*)d_in[4];
    const float* b_in    = (const float*)d_in[5];
    const float* W_state = (const float*)d_in[6];
    const float* b_state = (const float*)d_in[7];
    const float* W_out   = (const float*)d_in[8];
    const float* b_out   = (const float*)d_in[9];

    constexpr int T = 32, B = 256, DIN = 4196, H = 1024, C = 151;
    constexpr int M  = T * B;       // 8192
    constexpr int KP = 4224;        // DIN padded to multiple of 32
    constexpr int N6 = 6 * H;       // 6144
    constexpr int N5 = 5 * H;       // 5120

    size_t off = 0;
    auto carve = [&](size_t bytes) -> void* {
        void* p = (char*)d_ws + off;
        off += (bytes + 255) & ~(size_t)255;
        return p;
    };
    bf16*  pi  = (bf16*) carve((size_t)M * N6 * 2);          // 100.7 MB
    bf16*  wsb = (bf16*) carve((size_t)N5 * H * 2);          //  10.5 MB
    bf16*  wob = (bf16*) carve((size_t)192 * H * 2);         //   0.4 MB
    bf16*  hs  = (bf16*) carve((size_t)(T + 1) * B * H * 2); //  17.3 MB
    float* cst = (float*)carve((size_t)B * H * 4);           //   1.0 MB
    size_t base_need = off;

    bf16 *xb = nullptr, *wb = nullptr;
    bool precast = (ws_size >= base_need + (size_t)M * KP * 2 + (size_t)N6 * KP * 2 + 1024);
    if (precast) {
        xb = (bf16*)carve((size_t)M * KP * 2);               // 69.2 MB
        wb = (bf16*)carve((size_t)N6 * KP * 2);              // 51.9 MB
    }
    if (ws_size < base_need) {
        fprintf(stderr, "kernel_launch: ws too small (%zu < %zu)\n", ws_size, base_need);
        return;
    }

    // ---- init / weight casts ----
    hipLaunchKernelGGL(cast_f2b4_k, dim3((N5 * H / 4 + 255) / 256), dim3(256), 0, stream,
                       W_state, wsb, N5 * H / 4);
    hipLaunchKernelGGL(cast_wout_k, dim3(192 * H / 256), dim3(256), 0, stream, W_out, wob, C);
    hipLaunchKernelGGL(init_state_k, dim3(B * H / 256), dim3(256), 0, stream, c0, h0, cst, hs);

    // ---- big input-projection GEMM: pi = bf16(X @ W_in^T + b_in) ----
    if (precast) {
        hipLaunchKernelGGL(cast_pad4_k, dim3(M),  dim3(256), 0, stream, x,    xb, DIN, KP);
        hipLaunchKernelGGL(cast_pad4_k, dim3(N6), dim3(256), 0, stream, W_in, wb, DIN, KP);
        hipLaunchKernelGGL((gemm_lds_k<128, 128, true, false>),
                           dim3(N6 / 128, M / 128), dim3(256), 0, stream,
                           xb, wb, pi, b_in, KP, KP, KP, N6, N6);
    } else {
        hipLaunchKernelGGL((gemm_cast_k<128, 128>),
                           dim3(N6 / 128, M / 128), dim3(256), 0, stream,
                           x, W_in, pi, b_in, KP, DIN, DIN, DIN, N6);
    }

    // ---- recurrence: 32 fused step kernels (implicit inter-kernel sync) ----
    for (int t = 0; t < T; ++t) {
        hipLaunchKernelGGL(step_k2, dim3(H / 16, B / 64), dim3(512), 0, stream,
                           hs + (size_t)t * B * H, wsb,
                           pi + (size_t)t * B * N6, b_state,
                           cst, dmask,
                           hs + (size_t)(t + 1) * B * H);
    }

    // ---- output projection: logits = hs @ W_out^T + b_out ----
    hipLaunchKernelGGL((gemm_lds_k<128, 64, false, true>),
                       dim3(192 / 64, M / 128), dim3(256), 0, stream,
                       hs + (size_t)B * H, wob, (float*)d_out, b_out,
                       H, H, H, C, C);
}

// Round 5
// 1142.487 us; speedup vs baseline: 4.9366x; 1.1385x over previous
//
#include <hip/hip_runtime.h>
#include <hip/hip_bf16.h>
#include <cstdio>

typedef __bf16 bf16;
typedef __bf16 bf16x8 __attribute__((ext_vector_type(8)));
typedef __bf16 bf16x4 __attribute__((ext_vector_type(4)));
typedef float f32x4 __attribute__((ext_vector_type(4)));

__device__ __forceinline__ float sigmoidf_(float x) { return 1.f / (1.f + __expf(-x)); }
__device__ __forceinline__ float tanhf_(float x)    { return 1.f - 2.f / (__expf(2.f * x) + 1.f); }

// async global->LDS, 16 bytes per lane. LDS dest must be wave-uniform base +
// lane*16 (m104/m108): dest is always chunk-id * 16B with chunk tid-contiguous.
// Bank-conflict swizzle: LDS slot (row r, slot s) holds global chunk
// (r, s ^ (r&7)) of that row's 128B k-line. Readers invert: slot = want^(r&7).
__device__ __forceinline__ void gld_lds16(const bf16* g, bf16* l) {
    __builtin_amdgcn_global_load_lds(
        (const __attribute__((address_space(1))) void*)g,
        (__attribute__((address_space(3))) void*)l, 16, 0, 0);
}

// ---------------------------------------------------------------------------
// bf16 MFMA GEMM: C[M,N] = A[M,K] * B[N,K]^T + bias[N]. BK=64, swizzled LDS.
// Block 256 = 4 waves (2x2), wave tile (BM/2)x(BN/2). K % 64 == 0.
// ---------------------------------------------------------------------------
template<int BM, int BN, bool OUTBF16, bool NBOUND>
__global__ __launch_bounds__(256)
void gemm_lds_k(const bf16* __restrict__ A, const bf16* __restrict__ B,
                void* __restrict__ Cv, const float* __restrict__ bias,
                int K, int lda, int ldb, int ldc, int Nlim)
{
    constexpr int TM = BM / 32;
    constexpr int TN = BN / 32;

    __shared__ __align__(16) bf16 As[BM * 64];
    __shared__ __align__(16) bf16 Bs[BN * 64];

    const int tid  = threadIdx.x;
    const int wave = tid >> 6;
    const int lane = tid & 63;
    const int lrow = lane & 15;
    const int q    = lane >> 4;

    const int rowbase = blockIdx.y * BM;
    const int colbase = blockIdx.x * BN;
    const int wr = (wave >> 1) * (BM / 2);
    const int wc = (wave & 1) * (BN / 2);

    f32x4 acc[TM][TN] = {};

    for (int kk = 0; kk < K; kk += 64) {
        __syncthreads();
        // stage A: BM rows x 64 k = BM*8 chunks; source slot XOR-permuted
        #pragma unroll
        for (int i = 0; i < BM / 32; ++i) {
            int c  = tid + i * 256;
            int r  = c >> 3;
            int sl = c & 7;
            int ks = (sl ^ (r & 7)) * 8;
            gld_lds16(A + (size_t)(rowbase + r) * lda + kk + ks, &As[c * 8]);
        }
        #pragma unroll
        for (int i = 0; i < BN / 32; ++i) {
            int c  = tid + i * 256;
            int r  = c >> 3;
            int sl = c & 7;
            int ks = (sl ^ (r & 7)) * 8;
            gld_lds16(B + (size_t)(colbase + r) * ldb + kk + ks, &Bs[c * 8]);
        }
        __syncthreads();

        #pragma unroll
        for (int ks = 0; ks < 2; ++ks) {
            bf16x8 afr[TM], bfr[TN];
            #pragma unroll
            for (int m = 0; m < TM; ++m) {
                int r = wr + m * 16 + lrow;
                int s = ((ks << 2) | q) ^ (r & 7);
                afr[m] = *(const bf16x8*)&As[r * 64 + s * 8];
            }
            #pragma unroll
            for (int n = 0; n < TN; ++n) {
                int r = wc + n * 16 + lrow;
                int s = ((ks << 2) | q) ^ (r & 7);
                bfr[n] = *(const bf16x8*)&Bs[r * 64 + s * 8];
            }
            #pragma unroll
            for (int m = 0; m < TM; ++m)
                #pragma unroll
                for (int n = 0; n < TN; ++n)
                    acc[m][n] = __builtin_amdgcn_mfma_f32_16x16x32_bf16(
                                    afr[m], bfr[n], acc[m][n], 0, 0, 0);
        }
    }

    #pragma unroll
    for (int m = 0; m < TM; ++m) {
        #pragma unroll
        for (int n = 0; n < TN; ++n) {
            int gr0 = rowbase + wr + m * 16 + q * 4;
            int gc  = colbase + wc + n * 16 + lrow;
            bool cok = (!NBOUND) || (gc < Nlim);
            float bv = cok ? bias[gc] : 0.f;
            #pragma unroll
            for (int rix = 0; rix < 4; ++rix) {
                if (cok) {
                    float v = acc[m][n][rix] + bv;
                    size_t o = (size_t)(gr0 + rix) * ldc + gc;
                    if (OUTBF16) ((bf16*)Cv)[o] = (bf16)v;
                    else         ((float*)Cv)[o] = v;
                }
            }
        }
    }
}

// ---------------------------------------------------------------------------
// Fallback big GEMM (fp32 operands, cast during staging) if ws too small.
// ---------------------------------------------------------------------------
template<int BM, int BN>
__global__ __launch_bounds__(256)
void gemm_cast_k(const float* __restrict__ Av, const float* __restrict__ Bv,
                 bf16* __restrict__ Cv, const float* __restrict__ bias,
                 int K, int Klim, int lda, int ldb, int ldc)
{
    constexpr int TM = BM / 32;
    constexpr int TN = BN / 32;
    constexpr int LDK = 40;

    __shared__ __align__(16) bf16 As[BM * LDK];
    __shared__ __align__(16) bf16 Bs[BN * LDK];

    const int tid  = threadIdx.x;
    const int wave = tid >> 6;
    const int lane = tid & 63;
    const int lrow = lane & 15;
    const int q    = lane >> 4;

    const int rowbase = blockIdx.y * BM;
    const int colbase = blockIdx.x * BN;
    const int wr = (wave >> 1) * (BM / 2);
    const int wc = (wave & 1) * (BN / 2);

    f32x4 acc[TM][TN] = {};

    for (int kk = 0; kk < K; kk += 32) {
        __syncthreads();
        #pragma unroll
        for (int i = 0; i < BM / 64; ++i) {
            int c = tid + i * 256;
            int r = c >> 2, kc = (c & 3) * 8, kg = kk + kc;
            const float* src = Av + (size_t)(rowbase + r) * lda + kg;
            bf16x8 v;
            if (kg + 8 <= Klim) {
                float4 f0 = *(const float4*)(src);
                float4 f1 = *(const float4*)(src + 4);
                v[0]=(bf16)f0.x; v[1]=(bf16)f0.y; v[2]=(bf16)f0.z; v[3]=(bf16)f0.w;
                v[4]=(bf16)f1.x; v[5]=(bf16)f1.y; v[6]=(bf16)f1.z; v[7]=(bf16)f1.w;
            } else {
                #pragma unroll
                for (int e = 0; e < 8; ++e) v[e] = (kg + e < Klim) ? (bf16)src[e] : (bf16)0.f;
            }
            *(bf16x8*)&As[r * LDK + kc] = v;
        }
        #pragma unroll
        for (int i = 0; i < BN / 64; ++i) {
            int c = tid + i * 256;
            int r = c >> 2, kc = (c & 3) * 8, kg = kk + kc;
            const float* src = Bv + (size_t)(colbase + r) * ldb + kg;
            bf16x8 v;
            if (kg + 8 <= Klim) {
                float4 f0 = *(const float4*)(src);
                float4 f1 = *(const float4*)(src + 4);
                v[0]=(bf16)f0.x; v[1]=(bf16)f0.y; v[2]=(bf16)f0.z; v[3]=(bf16)f0.w;
                v[4]=(bf16)f1.x; v[5]=(bf16)f1.y; v[6]=(bf16)f1.z; v[7]=(bf16)f1.w;
            } else {
                #pragma unroll
                for (int e = 0; e < 8; ++e) v[e] = (kg + e < Klim) ? (bf16)src[e] : (bf16)0.f;
            }
            *(bf16x8*)&Bs[r * LDK + kc] = v;
        }
        __syncthreads();

        bf16x8 afr[TM], bfr[TN];
        #pragma unroll
        for (int m = 0; m < TM; ++m)
            afr[m] = *(const bf16x8*)&As[(wr + m * 16 + lrow) * LDK + q * 8];
        #pragma unroll
        for (int n = 0; n < TN; ++n)
            bfr[n] = *(const bf16x8*)&Bs[(wc + n * 16 + lrow) * LDK + q * 8];
        #pragma unroll
        for (int m = 0; m < TM; ++m)
            #pragma unroll
            for (int n = 0; n < TN; ++n)
                acc[m][n] = __builtin_amdgcn_mfma_f32_16x16x32_bf16(
                                afr[m], bfr[n], acc[m][n], 0, 0, 0);
    }

    #pragma unroll
    for (int m = 0; m < TM; ++m) {
        #pragma unroll
        for (int n = 0; n < TN; ++n) {
            int gr0 = rowbase + wr + m * 16 + q * 4;
            int gc  = colbase + wc + n * 16 + lrow;
            float bv = bias[gc];
            #pragma unroll
            for (int rix = 0; rix < 4; ++rix)
                Cv[(size_t)(gr0 + rix) * ldc + gc] = (bf16)(acc[m][n][rix] + bv);
        }
    }
}

// ---------------------------------------------------------------------------
// Fused recurrent step v3. Block = 512 threads (8 waves), grid (H/16=64, B/64=4).
// K=1024 split in two halves, one per 4-wave group; swizzled 128B-row LDS
// tiles; halves summed via LDS; gates in-register (no shuffles).
// ---------------------------------------------------------------------------
__global__ __launch_bounds__(512)
void step_k2(const bf16*  __restrict__ hprev,   // [256][1024]
             const bf16*  __restrict__ wsb,     // [5120][1024]
             const bf16*  __restrict__ pi_t,    // [256][6144] (b_in included)
             const float* __restrict__ b_state, // [5120]
             float*       __restrict__ cst,     // [256][1024]
             const float* __restrict__ dmask,   // [256][1024]
             bf16*        __restrict__ hnext)   // [256][1024]
{
    // 36 KB: A[2][64*64] (16KB) + B[2][80*64] (20KB); epilogue float reduction
    // (20KB) aliases the front.
    __shared__ __align__(16) unsigned char smem[36864];
    bf16* Asb = (bf16*)smem;                 // per group: [64 rows][64 k] swizzled
    bf16* Bsb = (bf16*)(smem + 16384);       // per group: [80 rows][64 k] swizzled
    float* red = (float*)smem;               // [256][5][4]

    const int tid   = threadIdx.x;
    const int wv    = tid >> 6;
    const int g2    = wv >> 2;               // K-half group
    const int wg    = wv & 3;                // m-tile within group
    const int lane  = tid & 63;
    const int lrow  = lane & 15;
    const int q     = lane >> 4;
    const int lt    = tid & 255;             // thread id within group
    const int hbase = blockIdx.x * 16;
    const int bbase = blockIdx.y * 64;
    const int kbase = g2 * 512;

    bf16* Ag = Asb + g2 * 4096;
    bf16* Bg = Bsb + g2 * 5120;

    // ---- prefetch epilogue operands (group 0 only; drain during iter 0) ----
    const int b0   = bbase + wg * 16 + q * 4;
    const int hcol = hbase + lrow;
    bf16  pif[4][6];
    float crv[4], dmv[4], bsv[5];
    if (g2 == 0) {
        #pragma unroll
        for (int rix = 0; rix < 4; ++rix) {
            const bf16* pib = pi_t + (size_t)(b0 + rix) * 6144 + hcol;
            #pragma unroll
            for (int g = 0; g < 6; ++g) pif[rix][g] = pib[g * 1024];
            size_t j = (size_t)(b0 + rix) * 1024 + hcol;
            crv[rix] = cst[j];
            dmv[rix] = dmask[j];
        }
        #pragma unroll
        for (int g = 0; g < 5; ++g) bsv[g] = b_state[g * 1024 + hcol];
    }

    // ---- K-half pipeline: 8 iters of BK=64, swizzled LDS ----
    f32x4 acc[5] = {};
    for (int it = 0; it < 8; ++it) {
        const int kb = kbase + it * 64;
        __syncthreads();
        // A tile: 64 rows x 64 k -> 512 chunks
        #pragma unroll
        for (int i = 0; i < 2; ++i) {
            int c  = lt + i * 256;
            int r  = c >> 3, sl = c & 7;
            int ks = (sl ^ (r & 7)) * 8;
            gld_lds16(hprev + (size_t)(bbase + r) * 1024 + kb + ks, Ag + c * 8);
        }
        // B tile: 5 gates x 16 rows x 64 k -> 640 chunks
        #pragma unroll
        for (int i = 0; i < 3; ++i) {
            int c = lt + i * 256;
            if (c < 640) {
                int r  = c >> 3, sl = c & 7;
                int g  = r >> 4, hh = r & 15;
                int ks = (sl ^ (r & 7)) * 8;
                gld_lds16(wsb + (size_t)(g * 1024 + hbase + hh) * 1024 + kb + ks,
                          Bg + c * 8);
            }
        }
        __syncthreads();

        #pragma unroll
        for (int ks = 0; ks < 2; ++ks) {
            int ra = wg * 16 + lrow;
            int sa = ((ks << 2) | q) ^ (ra & 7);
            bf16x8 af = *(const bf16x8*)&Ag[ra * 64 + sa * 8];
            #pragma unroll
            for (int g = 0; g < 5; ++g) {
                int rb = g * 16 + lrow;
                int sb = ((ks << 2) | q) ^ (rb & 7);
                bf16x8 bv = *(const bf16x8*)&Bg[rb * 64 + sb * 8];
                acc[g] = __builtin_amdgcn_mfma_f32_16x16x32_bf16(af, bv, acc[g], 0, 0, 0);
            }
        }
    }

    // ---- combine K-halves ----
    __syncthreads();
    if (g2 == 1) {
        #pragma unroll
        for (int g = 0; g < 5; ++g)
            *(f32x4*)&red[(lt * 5 + g) * 4] = acc[g];
    }
    __syncthreads();
    if (g2 == 0) {
        #pragma unroll
        for (int g = 0; g < 5; ++g)
            acc[g] += *(const f32x4*)&red[(lt * 5 + g) * 4];

        #pragma unroll
        for (int rix = 0; rix < 4; ++rix) {
            int b = b0 + rix;
            float p0 = acc[0][rix] + bsv[0] + (float)pif[rix][0];
            float p1 = acc[1][rix] + bsv[1] + (float)pif[rix][1];
            float p2 = acc[2][rix] + bsv[2] + (float)pif[rix][2];
            float p3 = acc[3][rix] + bsv[3] + (float)pif[rix][3];
            float p4 = acc[4][rix] + bsv[4] + (float)pif[rix][4];
            float p5 = (float)pif[rix][5];

            float ig = sigmoidf_(p0);
            float fg = sigmoidf_(p1);
            float mi = tanhf_(p2);
            float og = sigmoidf_(p3);
            float hw = sigmoidf_(p4);

            size_t j = (size_t)b * 1024 + hcol;
            float mem = ig * mi + fg * crv[rix];
            cst[j] = mem;
            float out = og * tanhf_(mem);
            out = hw * out + (1.f - hw) * p5;
            out *= dmv[rix];
            hnext[j] = (bf16)out;
        }
    }
}

// ---------------------------------------------------------------------------
// casts / init
// ---------------------------------------------------------------------------
__global__ void cast_f2b4_k(const float* __restrict__ src, bf16* __restrict__ dst, int n4) {
    int i = blockIdx.x * 256 + threadIdx.x;
    if (i < n4) {
        float4 f = *(const float4*)(src + i * 4);
        bf16x4 v; v[0]=(bf16)f.x; v[1]=(bf16)f.y; v[2]=(bf16)f.z; v[3]=(bf16)f.w;
        *(bf16x4*)(dst + i * 4) = v;
    }
}

// W_out [C,H] -> bf16 [192,H], rows >= C zero-filled
__global__ void cast_wout_k(const float* __restrict__ src, bf16* __restrict__ dst, int Crows) {
    int i = blockIdx.x * 256 + threadIdx.x;    // over 192*1024
    int r = i >> 10;
    dst[i] = (r < Crows) ? (bf16)src[i] : (bf16)0.f;
}

// row-wise cast with K padding (vec4): src [rows, klim] f32 -> dst [rows, kp] bf16
__global__ void cast_pad4_k(const float* __restrict__ src, bf16* __restrict__ dst,
                            int klim, int kp) {
    int r = blockIdx.x;
    const float* s = src + (size_t)r * klim;
    bf16* d = dst + (size_t)r * kp;
    int nk4 = kp >> 2, lim4 = klim >> 2;
    for (int c = threadIdx.x; c < nk4; c += 256) {
        bf16x4 v;
        if (c < lim4) {
            float4 f = *(const float4*)(s + c * 4);
            v[0]=(bf16)f.x; v[1]=(bf16)f.y; v[2]=(bf16)f.z; v[3]=(bf16)f.w;
        } else {
            v[0]=v[1]=v[2]=v[3]=(bf16)0.f;
        }
        *(bf16x4*)(d + c * 4) = v;
    }
}

__global__ void init_state_k(const float* __restrict__ c0, const float* __restrict__ h0,
                             float* __restrict__ cst, bf16* __restrict__ hs0) {
    int i = blockIdx.x * 256 + threadIdx.x;
    cst[i] = c0[i];
    hs0[i] = (bf16)h0[i];
}

// ---------------------------------------------------------------------------
extern "C" void kernel_launch(void* const* d_in, const int* in_sizes, int n_in,
                              void* d_out, int out_size, void* d_ws, size_t ws_size,
                              hipStream_t stream)
{
    const float* x       = (const float*)d_in[0];
    const float* h0      = (const float*)d_in[1];
    const float* c0      = (const float*)d_in[2];
    const float* dmask   = (const float*)d_in[3];
    const float* W_in    = (const float*)d_in[4];
    const float* b_in    = (const float*)d_in[5];
    const float* W_state = (const float*)d_in[6];
    const float* b_state = (const float*)d_in[7];
    const float* W_out   = (const float*)d_in[8];
    const float* b_out   = (const float*)d_in[9];

    constexpr int T = 32, B = 256, DIN = 4196, H = 1024, C = 151;
    constexpr int M  = T * B;       // 8192
    constexpr int KP = 4224;        // DIN padded to multiple of 64
    constexpr int N6 = 6 * H;       // 6144
    constexpr int N5 = 5 * H;       // 5120

    size_t off = 0;
    auto carve = [&](size_t bytes) -> void* {
        void* p = (char*)d_ws + off;
        off += (bytes + 255) & ~(size_t)255;
        return p;
    };
    bf16*  pi  = (bf16*) carve((size_t)M * N6 * 2);          // 100.7 MB
    bf16*  wsb = (bf16*) carve((size_t)N5 * H * 2);          //  10.5 MB
    bf16*  wob = (bf16*) carve((size_t)192 * H * 2);         //   0.4 MB
    bf16*  hs  = (bf16*) carve((size_t)(T + 1) * B * H * 2); //  17.3 MB
    float* cst = (float*)carve((size_t)B * H * 4);           //   1.0 MB
    size_t base_need = off;

    bf16 *xb = nullptr, *wb = nullptr;
    bool precast = (ws_size >= base_need + (size_t)M * KP * 2 + (size_t)N6 * KP * 2 + 1024);
    if (precast) {
        xb = (bf16*)carve((size_t)M * KP * 2);               // 69.2 MB
        wb = (bf16*)carve((size_t)N6 * KP * 2);              // 51.9 MB
    }
    if (ws_size < base_need) {
        fprintf(stderr, "kernel_launch: ws too small (%zu < %zu)\n", ws_size, base_need);
        return;
    }

    // ---- init / weight casts ----
    hipLaunchKernelGGL(cast_f2b4_k, dim3((N5 * H / 4 + 255) / 256), dim3(256), 0, stream,
                       W_state, wsb, N5 * H / 4);
    hipLaunchKernelGGL(cast_wout_k, dim3(192 * H / 256), dim3(256), 0, stream, W_out, wob, C);
    hipLaunchKernelGGL(init_state_k, dim3(B * H / 256), dim3(256), 0, stream, c0, h0, cst, hs);

    // ---- big input-projection GEMM: pi = bf16(X @ W_in^T + b_in) ----
    if (precast) {
        hipLaunchKernelGGL(cast_pad4_k, dim3(M),  dim3(256), 0, stream, x,    xb, DIN, KP);
        hipLaunchKernelGGL(cast_pad4_k, dim3(N6), dim3(256), 0, stream, W_in, wb, DIN, KP);
        hipLaunchKernelGGL((gemm_lds_k<128, 128, true, false>),
                           dim3(N6 / 128, M / 128), dim3(256), 0, stream,
                           xb, wb, pi, b_in, KP, KP, KP, N6, N6);
    } else {
        hipLaunchKernelGGL((gemm_cast_k<128, 128>),
                           dim3(N6 / 128, M / 128), dim3(256), 0, stream,
                           x, W_in, pi, b_in, KP, DIN, DIN, DIN, N6);
    }

    // ---- recurrence: 32 fused step kernels (implicit inter-kernel sync) ----
    for (int t = 0; t < T; ++t) {
        hipLaunchKernelGGL(step_k2, dim3(H / 16, B / 64), dim3(512), 0, stream,
                           hs + (size_t)t * B * H, wsb,
                           pi + (size_t)t * B * N6, b_state,
                           cst, dmask,
                           hs + (size_t)(t + 1) * B * H);
    }

    // ---- output projection: logits = hs @ W_out^T + b_out ----
    hipLaunchKernelGGL((gemm_lds_k<128, 64, false, true>),
                       dim3(192 / 64, M / 128), dim3(256), 0, stream,
                       hs + (size_t)B * H, wob, (float*)d_out, b_out,
                       H, H, H, C, C);
}

// Round 6
// 1132.455 us; speedup vs baseline: 4.9803x; 1.0089x over previous
//
#include <hip/hip_runtime.h>
#include <hip/hip_bf16.h>
#include <cstdio>

typedef __bf16 bf16;
typedef __bf16 bf16x8 __attribute__((ext_vector_type(8)));
typedef __bf16 bf16x4 __attribute__((ext_vector_type(4)));
typedef float f32x4 __attribute__((ext_vector_type(4)));

__device__ __forceinline__ float sigmoidf_(float x) { return 1.f / (1.f + __expf(-x)); }
__device__ __forceinline__ float tanhf_(float x)    { return 1.f - 2.f / (__expf(2.f * x) + 1.f); }

// async global->LDS, 16 bytes per lane. LDS dest must be wave-uniform base +
// lane*16 (m104/m108): dest is always chunk-id * 16B with chunk tid-contiguous.
// Bank-conflict swizzle: LDS slot (row r, slot s) holds global chunk
// (r, s ^ (r&7)) of that row's 128B k-line. Readers invert: slot = want^(r&7).
__device__ __forceinline__ void gld_lds16(const bf16* g, bf16* l) {
    __builtin_amdgcn_global_load_lds(
        (const __attribute__((address_space(1))) void*)g,
        (__attribute__((address_space(3))) void*)l, 16, 0, 0);
}

// ---------------------------------------------------------------------------
// bf16 MFMA GEMM: C[M,N] = A[M,K] * B[N,K]^T + bias[N]. BK=64, swizzled LDS.
// Block 256 = 4 waves (2x2), wave tile (BM/2)x(BN/2). K % 64 == 0.
// ---------------------------------------------------------------------------
template<int BM, int BN, bool OUTBF16, bool NBOUND>
__global__ __launch_bounds__(256)
void gemm_lds_k(const bf16* __restrict__ A, const bf16* __restrict__ B,
                void* __restrict__ Cv, const float* __restrict__ bias,
                int K, int lda, int ldb, int ldc, int Nlim)
{
    constexpr int TM = BM / 32;
    constexpr int TN = BN / 32;

    __shared__ __align__(16) bf16 As[BM * 64];
    __shared__ __align__(16) bf16 Bs[BN * 64];

    const int tid  = threadIdx.x;
    const int wave = tid >> 6;
    const int lane = tid & 63;
    const int lrow = lane & 15;
    const int q    = lane >> 4;

    const int rowbase = blockIdx.y * BM;
    const int colbase = blockIdx.x * BN;
    const int wr = (wave >> 1) * (BM / 2);
    const int wc = (wave & 1) * (BN / 2);

    f32x4 acc[TM][TN] = {};

    for (int kk = 0; kk < K; kk += 64) {
        __syncthreads();
        // stage A: BM rows x 64 k = BM*8 chunks; source slot XOR-permuted
        #pragma unroll
        for (int i = 0; i < BM / 32; ++i) {
            int c  = tid + i * 256;
            int r  = c >> 3;
            int sl = c & 7;
            int ks = (sl ^ (r & 7)) * 8;
            gld_lds16(A + (size_t)(rowbase + r) * lda + kk + ks, &As[c * 8]);
        }
        #pragma unroll
        for (int i = 0; i < BN / 32; ++i) {
            int c  = tid + i * 256;
            int r  = c >> 3;
            int sl = c & 7;
            int ks = (sl ^ (r & 7)) * 8;
            gld_lds16(B + (size_t)(colbase + r) * ldb + kk + ks, &Bs[c * 8]);
        }
        __syncthreads();

        #pragma unroll
        for (int ks = 0; ks < 2; ++ks) {
            bf16x8 afr[TM], bfr[TN];
            #pragma unroll
            for (int m = 0; m < TM; ++m) {
                int r = wr + m * 16 + lrow;
                int s = ((ks << 2) | q) ^ (r & 7);
                afr[m] = *(const bf16x8*)&As[r * 64 + s * 8];
            }
            #pragma unroll
            for (int n = 0; n < TN; ++n) {
                int r = wc + n * 16 + lrow;
                int s = ((ks << 2) | q) ^ (r & 7);
                bfr[n] = *(const bf16x8*)&Bs[r * 64 + s * 8];
            }
            #pragma unroll
            for (int m = 0; m < TM; ++m)
                #pragma unroll
                for (int n = 0; n < TN; ++n)
                    acc[m][n] = __builtin_amdgcn_mfma_f32_16x16x32_bf16(
                                    afr[m], bfr[n], acc[m][n], 0, 0, 0);
        }
    }

    #pragma unroll
    for (int m = 0; m < TM; ++m) {
        #pragma unroll
        for (int n = 0; n < TN; ++n) {
            int gr0 = rowbase + wr + m * 16 + q * 4;
            int gc  = colbase + wc + n * 16 + lrow;
            bool cok = (!NBOUND) || (gc < Nlim);
            float bv = cok ? bias[gc] : 0.f;
            #pragma unroll
            for (int rix = 0; rix < 4; ++rix) {
                if (cok) {
                    float v = acc[m][n][rix] + bv;
                    size_t o = (size_t)(gr0 + rix) * ldc + gc;
                    if (OUTBF16) ((bf16*)Cv)[o] = (bf16)v;
                    else         ((float*)Cv)[o] = v;
                }
            }
        }
    }
}

// ---------------------------------------------------------------------------
// Fallback big GEMM (fp32 operands, cast during staging) if ws too small.
// ---------------------------------------------------------------------------
template<int BM, int BN>
__global__ __launch_bounds__(256)
void gemm_cast_k(const float* __restrict__ Av, const float* __restrict__ Bv,
                 bf16* __restrict__ Cv, const float* __restrict__ bias,
                 int K, int Klim, int lda, int ldb, int ldc)
{
    constexpr int TM = BM / 32;
    constexpr int TN = BN / 32;
    constexpr int LDK = 40;

    __shared__ __align__(16) bf16 As[BM * LDK];
    __shared__ __align__(16) bf16 Bs[BN * LDK];

    const int tid  = threadIdx.x;
    const int wave = tid >> 6;
    const int lane = tid & 63;
    const int lrow = lane & 15;
    const int q    = lane >> 4;

    const int rowbase = blockIdx.y * BM;
    const int colbase = blockIdx.x * BN;
    const int wr = (wave >> 1) * (BM / 2);
    const int wc = (wave & 1) * (BN / 2);

    f32x4 acc[TM][TN] = {};

    for (int kk = 0; kk < K; kk += 32) {
        __syncthreads();
        #pragma unroll
        for (int i = 0; i < BM / 64; ++i) {
            int c = tid + i * 256;
            int r = c >> 2, kc = (c & 3) * 8, kg = kk + kc;
            const float* src = Av + (size_t)(rowbase + r) * lda + kg;
            bf16x8 v;
            if (kg + 8 <= Klim) {
                float4 f0 = *(const float4*)(src);
                float4 f1 = *(const float4*)(src + 4);
                v[0]=(bf16)f0.x; v[1]=(bf16)f0.y; v[2]=(bf16)f0.z; v[3]=(bf16)f0.w;
                v[4]=(bf16)f1.x; v[5]=(bf16)f1.y; v[6]=(bf16)f1.z; v[7]=(bf16)f1.w;
            } else {
                #pragma unroll
                for (int e = 0; e < 8; ++e) v[e] = (kg + e < Klim) ? (bf16)src[e] : (bf16)0.f;
            }
            *(bf16x8*)&As[r * LDK + kc] = v;
        }
        #pragma unroll
        for (int i = 0; i < BN / 64; ++i) {
            int c = tid + i * 256;
            int r = c >> 2, kc = (c & 3) * 8, kg = kk + kc;
            const float* src = Bv + (size_t)(colbase + r) * ldb + kg;
            bf16x8 v;
            if (kg + 8 <= Klim) {
                float4 f0 = *(const float4*)(src);
                float4 f1 = *(const float4*)(src + 4);
                v[0]=(bf16)f0.x; v[1]=(bf16)f0.y; v[2]=(bf16)f0.z; v[3]=(bf16)f0.w;
                v[4]=(bf16)f1.x; v[5]=(bf16)f1.y; v[6]=(bf16)f1.z; v[7]=(bf16)f1.w;
            } else {
                #pragma unroll
                for (int e = 0; e < 8; ++e) v[e] = (kg + e < Klim) ? (bf16)src[e] : (bf16)0.f;
            }
            *(bf16x8*)&Bs[r * LDK + kc] = v;
        }
        __syncthreads();

        bf16x8 afr[TM], bfr[TN];
        #pragma unroll
        for (int m = 0; m < TM; ++m)
            afr[m] = *(const bf16x8*)&As[(wr + m * 16 + lrow) * LDK + q * 8];
        #pragma unroll
        for (int n = 0; n < TN; ++n)
            bfr[n] = *(const bf16x8*)&Bs[(wc + n * 16 + lrow) * LDK + q * 8];
        #pragma unroll
        for (int m = 0; m < TM; ++m)
            #pragma unroll
            for (int n = 0; n < TN; ++n)
                acc[m][n] = __builtin_amdgcn_mfma_f32_16x16x32_bf16(
                                afr[m], bfr[n], acc[m][n], 0, 0, 0);
    }

    #pragma unroll
    for (int m = 0; m < TM; ++m) {
        #pragma unroll
        for (int n = 0; n < TN; ++n) {
            int gr0 = rowbase + wr + m * 16 + q * 4;
            int gc  = colbase + wc + n * 16 + lrow;
            float bv = bias[gc];
            #pragma unroll
            for (int rix = 0; rix < 4; ++rix)
                Cv[(size_t)(gr0 + rix) * ldc + gc] = (bf16)(acc[m][n][rix] + bv);
        }
    }
}

// ---------------------------------------------------------------------------
// Fused recurrent step v4. Block = 512 threads (8 waves), grid 1D = 256 with
// XCD-affinity remap: linear block ℓ lands on XCD ℓ%8 (round-robin dispatch
// heuristic), so we decode  slot=ℓ&7, btile=(ℓ>>3)&3, hb=(ℓ>>5)*8+slot.
// => all 4 batch-tiles of one h-tile share an XCD, and each XCD owns the SAME
// 8 h-tiles every step: its W slice (8*80 rows = 1.25 MB) stays L2-resident
// across all 32 step launches instead of streaming from L3 each step.
// K=1024 split in two halves, one per 4-wave group; swizzled 128B-row LDS
// tiles; halves summed via LDS; gates in-register (no shuffles).
// ---------------------------------------------------------------------------
__global__ __launch_bounds__(512)
void step_k2(const bf16*  __restrict__ hprev,   // [256][1024]
             const bf16*  __restrict__ wsb,     // [5120][1024]
             const bf16*  __restrict__ pi_t,    // [256][6144] (b_in included)
             const float* __restrict__ b_state, // [5120]
             float*       __restrict__ cst,     // [256][1024]
             const float* __restrict__ dmask,   // [256][1024]
             bf16*        __restrict__ hnext)   // [256][1024]
{
    // 36 KB: A[2][64*64] (16KB) + B[2][80*64] (20KB); epilogue float reduction
    // (20KB) aliases the front.
    __shared__ __align__(16) unsigned char smem[36864];
    bf16* Asb = (bf16*)smem;                 // per group: [64 rows][64 k] swizzled
    bf16* Bsb = (bf16*)(smem + 16384);       // per group: [80 rows][64 k] swizzled
    float* red = (float*)smem;               // [256][5][4]

    const int tid   = threadIdx.x;
    const int wv    = tid >> 6;
    const int g2    = wv >> 2;               // K-half group
    const int wg    = wv & 3;                // m-tile within group
    const int lane  = tid & 63;
    const int lrow  = lane & 15;
    const int q     = lane >> 4;
    const int lt    = tid & 255;             // thread id within group

    // XCD-affinity decode (see header comment)
    const int lb    = blockIdx.x;
    const int hb    = (lb >> 5) * 8 + (lb & 7);
    const int hbase = hb * 16;
    const int bbase = ((lb >> 3) & 3) * 64;
    const int kbase = g2 * 512;

    bf16* Ag = Asb + g2 * 4096;
    bf16* Bg = Bsb + g2 * 5120;

    // ---- prefetch epilogue operands (group 0 only; drain during iter 0) ----
    const int b0   = bbase + wg * 16 + q * 4;
    const int hcol = hbase + lrow;
    bf16  pif[4][6];
    float crv[4], dmv[4], bsv[5];
    if (g2 == 0) {
        #pragma unroll
        for (int rix = 0; rix < 4; ++rix) {
            const bf16* pib = pi_t + (size_t)(b0 + rix) * 6144 + hcol;
            #pragma unroll
            for (int g = 0; g < 6; ++g) pif[rix][g] = pib[g * 1024];
            size_t j = (size_t)(b0 + rix) * 1024 + hcol;
            crv[rix] = cst[j];
            dmv[rix] = dmask[j];
        }
        #pragma unroll
        for (int g = 0; g < 5; ++g) bsv[g] = b_state[g * 1024 + hcol];
    }

    // ---- K-half pipeline: 8 iters of BK=64, swizzled LDS ----
    f32x4 acc[5] = {};
    for (int it = 0; it < 8; ++it) {
        const int kb = kbase + it * 64;
        __syncthreads();
        // A tile: 64 rows x 64 k -> 512 chunks
        #pragma unroll
        for (int i = 0; i < 2; ++i) {
            int c  = lt + i * 256;
            int r  = c >> 3, sl = c & 7;
            int ks = (sl ^ (r & 7)) * 8;
            gld_lds16(hprev + (size_t)(bbase + r) * 1024 + kb + ks, Ag + c * 8);
        }
        // B tile: 5 gates x 16 rows x 64 k -> 640 chunks
        #pragma unroll
        for (int i = 0; i < 3; ++i) {
            int c = lt + i * 256;
            if (c < 640) {
                int r  = c >> 3, sl = c & 7;
                int g  = r >> 4, hh = r & 15;
                int ks = (sl ^ (r & 7)) * 8;
                gld_lds16(wsb + (size_t)(g * 1024 + hbase + hh) * 1024 + kb + ks,
                          Bg + c * 8);
            }
        }
        __syncthreads();

        #pragma unroll
        for (int ks = 0; ks < 2; ++ks) {
            int ra = wg * 16 + lrow;
            int sa = ((ks << 2) | q) ^ (ra & 7);
            bf16x8 af = *(const bf16x8*)&Ag[ra * 64 + sa * 8];
            #pragma unroll
            for (int g = 0; g < 5; ++g) {
                int rb = g * 16 + lrow;
                int sb = ((ks << 2) | q) ^ (rb & 7);
                bf16x8 bv = *(const bf16x8*)&Bg[rb * 64 + sb * 8];
                acc[g] = __builtin_amdgcn_mfma_f32_16x16x32_bf16(af, bv, acc[g], 0, 0, 0);
            }
        }
    }

    // ---- combine K-halves ----
    __syncthreads();
    if (g2 == 1) {
        #pragma unroll
        for (int g = 0; g < 5; ++g)
            *(f32x4*)&red[(lt * 5 + g) * 4] = acc[g];
    }
    __syncthreads();
    if (g2 == 0) {
        #pragma unroll
        for (int g = 0; g < 5; ++g)
            acc[g] += *(const f32x4*)&red[(lt * 5 + g) * 4];

        #pragma unroll
        for (int rix = 0; rix < 4; ++rix) {
            int b = b0 + rix;
            float p0 = acc[0][rix] + bsv[0] + (float)pif[rix][0];
            float p1 = acc[1][rix] + bsv[1] + (float)pif[rix][1];
            float p2 = acc[2][rix] + bsv[2] + (float)pif[rix][2];
            float p3 = acc[3][rix] + bsv[3] + (float)pif[rix][3];
            float p4 = acc[4][rix] + bsv[4] + (float)pif[rix][4];
            float p5 = (float)pif[rix][5];

            float ig = sigmoidf_(p0);
            float fg = sigmoidf_(p1);
            float mi = tanhf_(p2);
            float og = sigmoidf_(p3);
            float hw = sigmoidf_(p4);

            size_t j = (size_t)b * 1024 + hcol;
            float mem = ig * mi + fg * crv[rix];
            cst[j] = mem;
            float out = og * tanhf_(mem);
            out = hw * out + (1.f - hw) * p5;
            out *= dmv[rix];
            hnext[j] = (bf16)out;
        }
    }
}

// ---------------------------------------------------------------------------
// casts / init
// ---------------------------------------------------------------------------
__global__ void cast_f2b4_k(const float* __restrict__ src, bf16* __restrict__ dst, int n4) {
    int i = blockIdx.x * 256 + threadIdx.x;
    if (i < n4) {
        float4 f = *(const float4*)(src + i * 4);
        bf16x4 v; v[0]=(bf16)f.x; v[1]=(bf16)f.y; v[2]=(bf16)f.z; v[3]=(bf16)f.w;
        *(bf16x4*)(dst + i * 4) = v;
    }
}

// W_out [C,H] -> bf16 [192,H], rows >= C zero-filled
__global__ void cast_wout_k(const float* __restrict__ src, bf16* __restrict__ dst, int Crows) {
    int i = blockIdx.x * 256 + threadIdx.x;    // over 192*1024
    int r = i >> 10;
    dst[i] = (r < Crows) ? (bf16)src[i] : (bf16)0.f;
}

// row-wise cast with K padding (vec4): src [rows, klim] f32 -> dst [rows, kp] bf16
__global__ void cast_pad4_k(const float* __restrict__ src, bf16* __restrict__ dst,
                            int klim, int kp) {
    int r = blockIdx.x;
    const float* s = src + (size_t)r * klim;
    bf16* d = dst + (size_t)r * kp;
    int nk4 = kp >> 2, lim4 = klim >> 2;
    for (int c = threadIdx.x; c < nk4; c += 256) {
        bf16x4 v;
        if (c < lim4) {
            float4 f = *(const float4*)(s + c * 4);
            v[0]=(bf16)f.x; v[1]=(bf16)f.y; v[2]=(bf16)f.z; v[3]=(bf16)f.w;
        } else {
            v[0]=v[1]=v[2]=v[3]=(bf16)0.f;
        }
        *(bf16x4*)(d + c * 4) = v;
    }
}

__global__ void init_state_k(const float* __restrict__ c0, const float* __restrict__ h0,
                             float* __restrict__ cst, bf16* __restrict__ hs0) {
    int i = blockIdx.x * 256 + threadIdx.x;
    cst[i] = c0[i];
    hs0[i] = (bf16)h0[i];
}

// ---------------------------------------------------------------------------
extern "C" void kernel_launch(void* const* d_in, const int* in_sizes, int n_in,
                              void* d_out, int out_size, void* d_ws, size_t ws_size,
                              hipStream_t stream)
{
    const float* x       = (const float*)d_in[0];
    const float* h0      = (const float*)d_in[1];
    const float* c0      = (const float*)d_in[2];
    const float* dmask   = (const float*)d_in[3];
    const float* W_in    = (const float*)d_in[4];
    const float* b_in    = (const float*)d_in[5];
    const float* W_state = (const float*)d_in[6];
    const float* b_state = (const float*)d_in[7];
    const float* W_out   = (const float*)d_in[8];
    const float* b_out   = (const float*)d_in[9];

    constexpr int T = 32, B = 256, DIN = 4196, H = 1024, C = 151;
    constexpr int M  = T * B;       // 8192
    constexpr int KP = 4224;        // DIN padded to multiple of 64
    constexpr int N6 = 6 * H;       // 6144
    constexpr int N5 = 5 * H;       // 5120

    size_t off = 0;
    auto carve = [&](size_t bytes) -> void* {
        void* p = (char*)d_ws + off;
        off += (bytes + 255) & ~(size_t)255;
        return p;
    };
    bf16*  pi  = (bf16*) carve((size_t)M * N6 * 2);          // 100.7 MB
    bf16*  wsb = (bf16*) carve((size_t)N5 * H * 2);          //  10.5 MB
    bf16*  wob = (bf16*) carve((size_t)192 * H * 2);         //   0.4 MB
    bf16*  hs  = (bf16*) carve((size_t)(T + 1) * B * H * 2); //  17.3 MB
    float* cst = (float*)carve((size_t)B * H * 4);           //   1.0 MB
    size_t base_need = off;

    bf16 *xb = nullptr, *wb = nullptr;
    bool precast = (ws_size >= base_need + (size_t)M * KP * 2 + (size_t)N6 * KP * 2 + 1024);
    if (precast) {
        xb = (bf16*)carve((size_t)M * KP * 2);               // 69.2 MB
        wb = (bf16*)carve((size_t)N6 * KP * 2);              // 51.9 MB
    }
    if (ws_size < base_need) {
        fprintf(stderr, "kernel_launch: ws too small (%zu < %zu)\n", ws_size, base_need);
        return;
    }

    // ---- init / weight casts ----
    hipLaunchKernelGGL(cast_f2b4_k, dim3((N5 * H / 4 + 255) / 256), dim3(256), 0, stream,
                       W_state, wsb, N5 * H / 4);
    hipLaunchKernelGGL(cast_wout_k, dim3(192 * H / 256), dim3(256), 0, stream, W_out, wob, C);
    hipLaunchKernelGGL(init_state_k, dim3(B * H / 256), dim3(256), 0, stream, c0, h0, cst, hs);

    // ---- big input-projection GEMM: pi = bf16(X @ W_in^T + b_in) ----
    if (precast) {
        hipLaunchKernelGGL(cast_pad4_k, dim3(M),  dim3(256), 0, stream, x,    xb, DIN, KP);
        hipLaunchKernelGGL(cast_pad4_k, dim3(N6), dim3(256), 0, stream, W_in, wb, DIN, KP);
        hipLaunchKernelGGL((gemm_lds_k<128, 128, true, false>),
                           dim3(N6 / 128, M / 128), dim3(256), 0, stream,
                           xb, wb, pi, b_in, KP, KP, KP, N6, N6);
    } else {
        hipLaunchKernelGGL((gemm_cast_k<128, 128>),
                           dim3(N6 / 128, M / 128), dim3(256), 0, stream,
                           x, W_in, pi, b_in, KP, DIN, DIN, DIN, N6);
    }

    // ---- recurrence: 32 fused step kernels (implicit inter-kernel sync) ----
    for (int t = 0; t < T; ++t) {
        hipLaunchKernelGGL(step_k2, dim3(256), dim3(512), 0, stream,
                           hs + (size_t)t * B * H, wsb,
                           pi + (size_t)t * B * N6, b_state,
                           cst, dmask,
                           hs + (size_t)(t + 1) * B * H);
    }

    // ---- output projection: logits = hs @ W_out^T + b_out ----
    hipLaunchKernelGGL((gemm_lds_k<128, 64, false, true>),
                       dim3(192 / 64, M / 128), dim3(256), 0, stream,
                       hs + (size_t)B * H, wob, (float*)d_out, b_out,
                       H, H, H, C, C);
}